// Round 3
// baseline (13401.201 us; speedup 1.0000x reference)
//
#include <hip/hip_runtime.h>

typedef unsigned short ushort_t;
typedef __attribute__((ext_vector_type(8))) short s16x8;
typedef __attribute__((ext_vector_type(4))) float f32x4;

#define T_STEPS 128
#define BATCH   128
#define KIN     512
#define HDIM    2048
#define KTOT    2560    // KIN + HDIM
#define NPACK   8192    // 4*HDIM
#define NKT     40      // KTOT/64
#define OUTDIM  512

#define SBAR()   asm volatile("s_barrier" ::: "memory")
#define WAITV(n) asm volatile("s_waitcnt vmcnt(" #n ")" ::: "memory")

__device__ __forceinline__ ushort_t f2bf(float f){
  union{float f;unsigned u;} v; v.f=f;
  unsigned r = v.u + 0x7fffu + ((v.u>>16)&1u);
  return (ushort_t)(r>>16);
}
__device__ __forceinline__ float bf2f(ushort_t u){
  union{unsigned u;float f;} v; v.u = ((unsigned)u)<<16; return v.f;
}
__device__ __forceinline__ float sigmoidf_(float x){ return 1.f/(1.f+__expf(-x)); }
__device__ __forceinline__ float tanhf_(float x){ return 1.f-2.f/(__expf(2.f*x)+1.f); }
__device__ __forceinline__ f32x4 mfma16(s16x8 a, s16x8 b, f32x4 c){
  return __builtin_amdgcn_mfma_f32_16x16x32_bf16(a,b,c,0,0,0);
}
__device__ __forceinline__ void gload16(const void* g, void* l){
  __builtin_amdgcn_global_load_lds((const __attribute__((address_space(1))) void*)g,
                                   (__attribute__((address_space(3))) void*)l, 16, 0, 0);
}

// ---------------- pack kernels ----------------

// Wp[n][k] (n-major, bf16) = W[k][src_col(n)], n<8192, k<2560.
// packed col n = slice8*32 + gate*8 + j  (slice8 = h>>3, j = h&7, gates i,f,o,c)
// src_col = gate*2048 + slice8*8 + j
__global__ __launch_bounds__(256) void pack_w(const float* __restrict__ Wx,
                                              const float* __restrict__ Wh,
                                              ushort_t* __restrict__ Wp){
  __shared__ ushort_t tile[64][72];
  int kT = blockIdx.x % NKT;        // 0..39
  int nT = blockIdx.x / NKT;        // 0..127
  int tx = threadIdx.x & 63;        // n within tile
  int ty = threadIdx.x >> 6;        // 0..3
  int s8 = 2*nT + (tx>>5);
  int g  = (tx>>3)&3;
  int j  = tx&7;
  int src_col = g*2048 + s8*8 + j;
  int k0 = kT*64;
  const float* W = (k0 < KIN) ? (Wx + (size_t)k0*NPACK)
                              : (Wh + (size_t)(k0-KIN)*NPACK);
  for (int kk = 0; kk < 64; kk += 4){
    int kl = kk + ty;
    tile[tx][kl] = f2bf(W[(size_t)kl*NPACK + src_col]);
  }
  __syncthreads();
  for (int rr = 0; rr < 64; rr += 4){
    int trow = rr + ty;
    Wp[(size_t)(nT*64 + trow)*KTOT + k0 + tx] = tile[trow][tx];
  }
}

// fcwT[n][k] (bf16) = fc_w[k][n], n<512, k<2048
__global__ __launch_bounds__(256) void pack_fcw(const float* __restrict__ fcw,
                                                ushort_t* __restrict__ fcwT){
  __shared__ ushort_t tile[64][72];
  int kT = blockIdx.x & 31;         // 0..31
  int nT = blockIdx.x >> 5;         // 0..7
  int tx = threadIdx.x & 63;
  int ty = threadIdx.x >> 6;
  int k0 = kT*64;
  int src_col = nT*64 + tx;
  for (int kk = 0; kk < 64; kk += 4){
    int kl = kk + ty;
    tile[tx][kl] = f2bf(fcw[(size_t)(k0+kl)*OUTDIM + src_col]);
  }
  __syncthreads();
  for (int rr = 0; rr < 64; rr += 4){
    int trow = rr + ty;
    fcwT[(size_t)(nT*64 + trow)*HDIM + k0 + tx] = tile[trow][tx];
  }
}

// prep: x -> bf16 into xh x-region; zero xh[0] h-region; combined bias (packed
// order); zero c (lives in d_out c-slot); zero barrier state.
__global__ __launch_bounds__(256) void prep(const float* __restrict__ x,
                                            const float* __restrict__ bx,
                                            const float* __restrict__ bh,
                                            ushort_t* __restrict__ xh,
                                            float* __restrict__ bias,
                                            float* __restrict__ cbuf,
                                            unsigned* __restrict__ bar){
  int idx = blockIdx.x*256 + threadIdx.x;          // 1,048,576 threads
  for (int i = idx; i < T_STEPS*BATCH*KIN; i += 1048576){
    int t = i / (BATCH*KIN);
    int r = (i / KIN) % BATCH;
    int k = i % KIN;
    xh[((size_t)t*BATCH + r)*KTOT + k] = f2bf(x[i]);
  }
  if (idx < BATCH*HDIM){
    int r = idx >> 11, k = idx & 2047;
    xh[(size_t)r*KTOT + KIN + k] = 0;              // h0 = 0
    cbuf[idx] = 0.f;                               // c0 = 0
  }
  if (idx < NPACK){
    int s8 = idx>>5, g = (idx>>3)&3, j = idx&7;
    int sc = g*2048 + s8*8 + j;
    bias[idx] = bx[sc] + bh[sc];
  }
  if (idx < 20480) bar[idx] = 0u;
}

// ---------------- persistent LSTM sequence kernel ----------------
// grid 256 x 512 threads (8 waves). Block tile: 64 batch rows x 64 packed cols.
// Weight slice (64 x 2560 bf16) register-resident for all 128 steps.
// Waves k-split 8 x 320; LDS pairwise reduction (64 KB); spin grid barrier.
__global__ __launch_bounds__(512, 2) void lstm_seq(const ushort_t* __restrict__ xh_c,
                                                   ushort_t* __restrict__ xh,
                                                   const ushort_t* __restrict__ Wp,
                                                   const float* __restrict__ bias,
                                                   float* __restrict__ cbuf,
                                                   unsigned* __restrict__ bar){
  __shared__ float red[4][64][64];                 // 65536 B
  const int tid = threadIdx.x;
  const int l = tid & 63, w = tid >> 6;            // lane, wave(=k-slice)
  const int lane16 = l & 15, q4 = l >> 4;
  const int bid = blockIdx.x;
  const int orig = (bid & 7)*32 + (bid >> 3);      // XCD-contiguous tiles
  const int rt = orig & 1;                         // row group (0/1)
  const int cb = orig >> 1;                        // col block (0..127)

  // ---- preload weights into registers: 4 n-frags x 10 k-frags ----
  s16x8 wfr[4][10];
#pragma unroll
  for (int nf = 0; nf < 4; ++nf){
    int n = cb*64 + nf*16 + lane16;
    const char* p = (const char*)Wp + ((size_t)n*KTOT + w*320 + q4*8)*2;
#pragma unroll
    for (int kf = 0; kf < 10; ++kf)
      wfr[nf][kf] = *(const s16x8*)(p + kf*64);
  }

  // ---- per-lane A voffsets (bytes) for 4 m-frags ----
  int voffA[4];
#pragma unroll
  for (int mf = 0; mf < 4; ++mf)
    voffA[mf] = ((rt*64 + mf*16 + lane16)*KTOT + w*320 + q4*8)*2;

  // ---- epilogue constants ----
  const int e0   = tid*2;            // first of 2 h-elements (same row)
  const int erow = e0 >> 4;          // 0..63
  const int ehc  = e0 & 15;          // even
  const int s8l  = ehc >> 3, jj = ehc & 7;
  const float* bb = bias + cb*64 + s8l*32 + jj;
  const float2 bI = *(const float2*)(bb +  0);
  const float2 bF = *(const float2*)(bb +  8);
  const float2 bO = *(const float2*)(bb + 16);
  const float2 bC = *(const float2*)(bb + 24);
  const int crow = rt*64 + erow;
  const int ccol = cb*16 + ehc;
  float* cptr = cbuf + (size_t)crow*HDIM + ccol;

  unsigned* grp  = bar;              // [128][8] stride-16 padded
  unsigned* root = bar + 16384;      // [128] stride-16
  unsigned* rel  = bar + 18432;      // [128] stride-16

#pragma unroll 1
  for (int t = 0; t < T_STEPS; ++t){
    const char* pA = (const char*)xh_c + (size_t)t*BATCH*KTOT*2;
    f32x4 acc[4][4] = {};
#pragma unroll
    for (int kf = 0; kf < 10; ++kf){
      s16x8 a0 = *(const s16x8*)(pA + voffA[0] + kf*64);
      s16x8 a1 = *(const s16x8*)(pA + voffA[1] + kf*64);
      s16x8 a2 = *(const s16x8*)(pA + voffA[2] + kf*64);
      s16x8 a3 = *(const s16x8*)(pA + voffA[3] + kf*64);
#pragma unroll
      for (int nf = 0; nf < 4; ++nf){
        acc[0][nf] = mfma16(a0, wfr[nf][kf], acc[0][nf]);
        acc[1][nf] = mfma16(a1, wfr[nf][kf], acc[1][nf]);
        acc[2][nf] = mfma16(a2, wfr[nf][kf], acc[2][nf]);
        acc[3][nf] = mfma16(a3, wfr[nf][kf], acc[3][nf]);
      }
    }

    // ---- reduction: 8 partials -> 4 (pairwise) -> sum in epilogue ----
    if (w >= 4){
      float (*rp)[64] = red[w-4];
#pragma unroll
      for (int mf = 0; mf < 4; ++mf)
#pragma unroll
        for (int nf = 0; nf < 4; ++nf)
#pragma unroll
          for (int r = 0; r < 4; ++r)
            rp[mf*16 + q4*4 + r][nf*16 + lane16] = acc[mf][nf][r];
    }
    __syncthreads();
    if (w < 4){
      float (*rp)[64] = red[w];
#pragma unroll
      for (int mf = 0; mf < 4; ++mf)
#pragma unroll
        for (int nf = 0; nf < 4; ++nf)
#pragma unroll
          for (int r = 0; r < 4; ++r)
            rp[mf*16 + q4*4 + r][nf*16 + lane16] += acc[mf][nf][r];
    }
    __syncthreads();

    // ---- epilogue: gates, c/h update (2 h-elems per thread) ----
    {
      float2 gI = {0,0}, gF = {0,0}, gO = {0,0}, gC = {0,0};
#pragma unroll
      for (int ks = 0; ks < 4; ++ks){
        const float* base = &red[ks][erow][s8l*32 + jj];
        float2 vI = *(const float2*)(base +  0);
        float2 vF = *(const float2*)(base +  8);
        float2 vO = *(const float2*)(base + 16);
        float2 vC = *(const float2*)(base + 24);
        gI.x += vI.x; gI.y += vI.y;  gF.x += vF.x; gF.y += vF.y;
        gO.x += vO.x; gO.y += vO.y;  gC.x += vC.x; gC.y += vC.y;
      }
      gI.x += bI.x; gI.y += bI.y;  gF.x += bF.x; gF.y += bF.y;
      gO.x += bO.x; gO.y += bO.y;  gC.x += bC.x; gC.y += bC.y;
      float2 cold = *(const float2*)cptr;
      float cn0 = sigmoidf_(gF.x)*cold.x + sigmoidf_(gI.x)*tanhf_(gC.x);
      float cn1 = sigmoidf_(gF.y)*cold.y + sigmoidf_(gI.y)*tanhf_(gC.y);
      float hn0 = sigmoidf_(gO.x)*tanhf_(cn0);
      float hn1 = sigmoidf_(gO.y)*tanhf_(cn1);
      float2 cnv; cnv.x = cn0; cnv.y = cn1;
      *(float2*)cptr = cnv;
      ushort_t h0 = f2bf(hn0), h1 = f2bf(hn1);
      unsigned hpack = ((unsigned)h1 << 16) | (unsigned)h0;
      *(unsigned*)(xh + ((size_t)(t+1)*BATCH + crow)*KTOT + KIN + ccol) = hpack;
    }

    // ---- grid barrier (skip after last step) ----
    if (t < T_STEPS-1){
      __threadfence();
      __syncthreads();
      if (tid == 0){
        unsigned old = __hip_atomic_fetch_add(&grp[t*128 + (bid&7)*16], 1u,
                          __ATOMIC_ACQ_REL, __HIP_MEMORY_SCOPE_AGENT);
        if (old == 31u){
          unsigned r2 = __hip_atomic_fetch_add(&root[t*16], 1u,
                          __ATOMIC_ACQ_REL, __HIP_MEMORY_SCOPE_AGENT);
          if (r2 == 7u)
            __hip_atomic_store(&rel[t*16], 1u,
                          __ATOMIC_RELEASE, __HIP_MEMORY_SCOPE_AGENT);
        }
        while (__hip_atomic_load(&rel[t*16],
                  __ATOMIC_ACQUIRE, __HIP_MEMORY_SCOPE_AGENT) == 0u){}
      }
      __syncthreads();
      __threadfence();
    }
  }
}

// ---------------- output GEMM: [16384,2048]x[2048,512] + fc_b ----------------
// A rows live inside xh: row m -> xh[(m+128)*KTOT + 512 + k]
__global__ __launch_bounds__(256) void out_gemm(const ushort_t* __restrict__ A,
                                                const ushort_t* __restrict__ Bt,
                                                const float* __restrict__ fcb,
                                                float* __restrict__ out){
  __shared__ alignas(16) ushort_t Alds[3][4096];
  __shared__ alignas(16) ushort_t Blds[3][4096];
  const int tid = threadIdx.x;
  const int l = tid & 63, w = tid >> 6;
  const int b = blockIdx.x;
  const int orig = (b & 7)*256 + (b >> 3);
  const int rowt = orig >> 3;
  const int colt = orig & 7;
  const int sc = (l&7) ^ (l>>3);
  const int q4 = l>>4, d = l&7;
  const int swz0 = (q4 ^ d) << 4;
  const int swz1 = ((4+q4) ^ d) << 4;
  const int mrow0 = ((w>>1)*32) + (l&15);
  const int nrow0 = ((w&1)*32) + (l&15);
  f32x4 acc[2][2] = {};

  auto stage = [&](int kt, int buf){
    int k0 = kt*64;
#pragma unroll
    for (int q = 0; q < 2; ++q){
      int rowl = q*32 + w*8 + (l>>3);
      gload16(A  + (size_t)(rowt*64 + rowl)*KTOT + k0 + sc*8, &Alds[buf][(q*32+w*8)*64]);
      gload16(Bt + (size_t)(colt*64 + rowl)*HDIM + k0 + sc*8, &Blds[buf][(q*32+w*8)*64]);
    }
  };

  stage(0, 0); stage(1, 1); stage(2, 2);
  int buf = 0;
  for (int kt = 0; kt < 32; ++kt){
    if (kt < 30)       { WAITV(8); }
    else if (kt == 30) { WAITV(4); }
    else               { WAITV(0); }
    SBAR();
    const char* pa = (const char*)Alds[buf];
    const char* pb = (const char*)Blds[buf];
#pragma unroll
    for (int s = 0; s < 2; ++s){
      int swz = s ? swz1 : swz0;
      s16x8 a0 = *(const s16x8*)(pa + mrow0*128 + swz);
      s16x8 a1 = *(const s16x8*)(pa + (mrow0+16)*128 + swz);
      s16x8 b0 = *(const s16x8*)(pb + nrow0*128 + swz);
      s16x8 b1 = *(const s16x8*)(pb + (nrow0+16)*128 + swz);
      acc[0][0] = mfma16(a0, b0, acc[0][0]);
      acc[0][1] = mfma16(a0, b1, acc[0][1]);
      acc[1][0] = mfma16(a1, b0, acc[1][0]);
      acc[1][1] = mfma16(a1, b1, acc[1][1]);
    }
    SBAR();
    if (kt+3 < 32) stage(kt+3, buf);
    buf = (buf==2) ? 0 : buf+1;
  }
#pragma unroll
  for (int m = 0; m < 2; ++m){
#pragma unroll
    for (int f = 0; f < 2; ++f){
      int col = colt*64 + (w&1)*32 + f*16 + (l&15);
      float bb = fcb[col];
#pragma unroll
      for (int r = 0; r < 4; ++r){
        int row = rowt*64 + (w>>1)*32 + m*16 + q4*4 + r;
        out[(size_t)row*OUTDIM + col] = acc[m][f][r] + bb;
      }
    }
  }
}

// final h (bf16->f32) into d_out; c already lives in its d_out slot
__global__ __launch_bounds__(256) void finalize(const ushort_t* __restrict__ xh,
                                                float* __restrict__ out){
  int i = blockIdx.x*256 + threadIdx.x;            // 131072 threads
  for (; i < BATCH*HDIM; i += 131072){
    int r = i >> 11, k = i & 2047;
    out[(size_t)T_STEPS*BATCH*OUTDIM + i] =
        bf2f(xh[((size_t)T_STEPS*BATCH + r)*KTOT + KIN + k]);
  }
}

extern "C" void kernel_launch(void* const* d_in, const int* in_sizes, int n_in,
                              void* d_out, int out_size, void* d_ws, size_t ws_size,
                              hipStream_t stream){
  const float* x   = (const float*)d_in[0];
  const float* Wx  = (const float*)d_in[1];
  const float* Wh  = (const float*)d_in[2];
  const float* bx  = (const float*)d_in[3];
  const float* bh  = (const float*)d_in[4];
  const float* fcw = (const float*)d_in[5];
  const float* fcb = (const float*)d_in[6];
  float* out = (float*)d_out;
  char* ws = (char*)d_ws;

  // ws layout (bytes)
  ushort_t* Wp   = (ushort_t*)(ws + 0);              // 41,943,040
  ushort_t* fcwT = (ushort_t*)(ws + 41943040);       //  2,097,152
  ushort_t* xh   = (ushort_t*)(ws + 44040192);       // 84,541,440 (129 slots x 128 x 2560 bf16)
  float*    bias = (float*)   (ws + 128581632);      //     32,768
  unsigned* bar  = (unsigned*)(ws + 128614400);      //     81,920
  if (ws_size < (size_t)128696320) return;           // insufficient scratch

  // c state lives directly in its output slot: out + T*B*O + B*H
  float* cbuf = out + (size_t)T_STEPS*BATCH*OUTDIM + (size_t)BATCH*HDIM;

  pack_w  <<<NKT*128, 256, 0, stream>>>(Wx, Wh, Wp);
  pack_fcw<<<32*8,    256, 0, stream>>>(fcw, fcwT);
  prep    <<<4096,    256, 0, stream>>>(x, bx, bh, xh, bias, cbuf, bar);
  lstm_seq<<<256, 512, 0, stream>>>(xh, xh, Wp, bias, cbuf, bar);
  out_gemm<<<2048, 256, 0, stream>>>(xh + (size_t)BATCH*KTOT + KIN, fcwT, fcb, out);
  finalize<<<512, 256, 0, stream>>>(xh, out);
}

// Round 4
// 1887.866 us; speedup vs baseline: 7.0986x; 7.0986x over previous
//
#include <hip/hip_runtime.h>

typedef unsigned short ushort_t;
typedef __attribute__((ext_vector_type(8))) short s16x8;
typedef __attribute__((ext_vector_type(4))) float f32x4;

#define T_STEPS 128
#define BATCH   128
#define KIN     512
#define HDIM    2048
#define KTOT    2560    // KIN + HDIM
#define NPACK   8192    // 4*HDIM
#define NKT     40      // KTOT/64
#define OUTDIM  512

#define SBAR()   asm volatile("s_barrier" ::: "memory")
#define WAITV(n) asm volatile("s_waitcnt vmcnt(" #n ")" ::: "memory")
#define SCHED0() __builtin_amdgcn_sched_barrier(0)

__device__ __forceinline__ ushort_t f2bf(float f){
  union{float f;unsigned u;} v; v.f=f;
  unsigned r = v.u + 0x7fffu + ((v.u>>16)&1u);
  return (ushort_t)(r>>16);
}
__device__ __forceinline__ float bf2f(ushort_t u){
  union{unsigned u;float f;} v; v.u = ((unsigned)u)<<16; return v.f;
}
__device__ __forceinline__ float sigmoidf_(float x){ return 1.f/(1.f+__expf(-x)); }
__device__ __forceinline__ float tanhf_(float x){ return 1.f-2.f/(__expf(2.f*x)+1.f); }
__device__ __forceinline__ f32x4 mfma16(s16x8 a, s16x8 b, f32x4 c){
  return __builtin_amdgcn_mfma_f32_16x16x32_bf16(a,b,c,0,0,0);
}
__device__ __forceinline__ void gload16(const void* g, void* l){
  __builtin_amdgcn_global_load_lds((const __attribute__((address_space(1))) void*)g,
                                   (__attribute__((address_space(3))) void*)l, 16, 0, 0);
}
// L2-bypass (device-coherent) store of one dword
__device__ __forceinline__ void store_u32_sc(void* p, unsigned v){
  asm volatile("global_store_dword %0, %1, off sc0 sc1" :: "v"(p), "v"(v) : "memory");
}

// issue one 16B A-load; SC chooses L2-bypass (h-region) vs cached (x-region)
#define GLD1(dst, ptr, IMMS, SC) \
  do{ if (SC) asm volatile("global_load_dwordx4 %0, %1, off offset:" IMMS " sc0 sc1" \
                           : "=v"(dst) : "v"(ptr)); \
      else    asm volatile("global_load_dwordx4 %0, %1, off offset:" IMMS \
                           : "=v"(dst) : "v"(ptr)); }while(0)

#define ISSUE(P, IMMS, SC) \
  GLD1(P##0, aB0, IMMS, SC); GLD1(P##1, aB1, IMMS, SC); \
  GLD1(P##2, aB2, IMMS, SC); GLD1(P##3, aB3, IMMS, SC)

#define COMP(P, KF) do{ \
  s16x8 b3_ = *(const s16x8*)(wbase + KF*64); \
  acc[0][0]=mfma16(P##0,wfr[0][KF],acc[0][0]); acc[1][0]=mfma16(P##1,wfr[0][KF],acc[1][0]); \
  acc[2][0]=mfma16(P##2,wfr[0][KF],acc[2][0]); acc[3][0]=mfma16(P##3,wfr[0][KF],acc[3][0]); \
  acc[0][1]=mfma16(P##0,wfr[1][KF],acc[0][1]); acc[1][1]=mfma16(P##1,wfr[1][KF],acc[1][1]); \
  acc[2][1]=mfma16(P##2,wfr[1][KF],acc[2][1]); acc[3][1]=mfma16(P##3,wfr[1][KF],acc[3][1]); \
  acc[0][2]=mfma16(P##0,wfr[2][KF],acc[0][2]); acc[1][2]=mfma16(P##1,wfr[2][KF],acc[1][2]); \
  acc[2][2]=mfma16(P##2,wfr[2][KF],acc[2][2]); acc[3][2]=mfma16(P##3,wfr[2][KF],acc[3][2]); \
  acc[0][3]=mfma16(P##0,b3_,acc[0][3]); acc[1][3]=mfma16(P##1,b3_,acc[1][3]); \
  acc[2][3]=mfma16(P##2,b3_,acc[2][3]); acc[3][3]=mfma16(P##3,b3_,acc[3][3]); }while(0)

// ---------------- pack kernels ----------------

__global__ __launch_bounds__(256) void pack_w(const float* __restrict__ Wx,
                                              const float* __restrict__ Wh,
                                              ushort_t* __restrict__ Wp){
  __shared__ ushort_t tile[64][72];
  int kT = blockIdx.x % NKT;
  int nT = blockIdx.x / NKT;
  int tx = threadIdx.x & 63;
  int ty = threadIdx.x >> 6;
  int s8 = 2*nT + (tx>>5);
  int g  = (tx>>3)&3;
  int j  = tx&7;
  int src_col = g*2048 + s8*8 + j;
  int k0 = kT*64;
  const float* W = (k0 < KIN) ? (Wx + (size_t)k0*NPACK)
                              : (Wh + (size_t)(k0-KIN)*NPACK);
  for (int kk = 0; kk < 64; kk += 4){
    int kl = kk + ty;
    tile[tx][kl] = f2bf(W[(size_t)kl*NPACK + src_col]);
  }
  __syncthreads();
  for (int rr = 0; rr < 64; rr += 4){
    int trow = rr + ty;
    Wp[(size_t)(nT*64 + trow)*KTOT + k0 + tx] = tile[trow][tx];
  }
}

__global__ __launch_bounds__(256) void pack_fcw(const float* __restrict__ fcw,
                                                ushort_t* __restrict__ fcwT){
  __shared__ ushort_t tile[64][72];
  int kT = blockIdx.x & 31;
  int nT = blockIdx.x >> 5;
  int tx = threadIdx.x & 63;
  int ty = threadIdx.x >> 6;
  int k0 = kT*64;
  int src_col = nT*64 + tx;
  for (int kk = 0; kk < 64; kk += 4){
    int kl = kk + ty;
    tile[tx][kl] = f2bf(fcw[(size_t)(k0+kl)*OUTDIM + src_col]);
  }
  __syncthreads();
  for (int rr = 0; rr < 64; rr += 4){
    int trow = rr + ty;
    fcwT[(size_t)(nT*64 + trow)*HDIM + k0 + tx] = tile[trow][tx];
  }
}

// prep: x->bf16 into xh x-region; h0=0 (L2-bypass stores so L3 owns them);
// combined bias (packed order); zero barrier words.
__global__ __launch_bounds__(256) void prep(const float* __restrict__ x,
                                            const float* __restrict__ bx,
                                            const float* __restrict__ bh,
                                            ushort_t* __restrict__ xh,
                                            float* __restrict__ bias,
                                            unsigned* __restrict__ bar){
  int idx = blockIdx.x*256 + threadIdx.x;          // 1,048,576 threads
  for (int i = idx; i < T_STEPS*BATCH*KIN; i += 1048576){
    int t = i / (BATCH*KIN);
    int r = (i / KIN) % BATCH;
    int k = i % KIN;
    xh[((size_t)t*BATCH + r)*KTOT + k] = f2bf(x[i]);
  }
  if (idx < BATCH*HDIM/2){
    int r = idx >> 10;
    int k2 = (idx & 1023)*2;
    store_u32_sc(xh + (size_t)r*KTOT + KIN + k2, 0u);
  }
  if (idx < NPACK){
    int s8 = idx>>5, g = (idx>>3)&3, j = idx&7;
    int sc = g*2048 + s8*8 + j;
    bias[idx] = bx[sc] + bh[sc];
  }
  if (idx < 1024) bar[idx] = 0u;
}

// ---------------- persistent LSTM sequence kernel ----------------
// grid 256 x 512 thr, 1 block/CU. Block tile: 64 rows x 64 packed cols.
// Weights: nf 0..2 (48 cols) in VGPRs, nf 3 (16 cols) in LDS. 8 waves k-split
// (320 k each). A-loads: x-part cached, h-part sc0sc1 (L3-coherent, no L2
// staleness, no fences). c-state in registers. Relaxed-atomic spin barrier.
__global__ __launch_bounds__(512) void lstm_seq(const ushort_t* __restrict__ xh_c,
                                                ushort_t* __restrict__ xh,
                                                const ushort_t* __restrict__ Wp,
                                                const float* __restrict__ bias,
                                                float* __restrict__ cbuf,
                                                unsigned* __restrict__ bar){
  __shared__ ushort_t wlds[16][2568];              // 82,176 B (pad 8 -> 2-way free)
  __shared__ float red[2][64][68];                 // 34,816 B  [slice][col][row-pad]
  const int tid = threadIdx.x;
  const int l = tid & 63, w = tid >> 6;
  const int lane16 = l & 15, q4 = l >> 4;
  const int bid = blockIdx.x;
  const int orig = (bid & 7)*32 + (bid >> 3);      // XCD-contiguous tiles
  const int rt = orig & 1;
  const int cb = orig >> 1;

  // ---- weights nf 0..2 into registers: 30 frags = 120 VGPR ----
  s16x8 wfr[3][10];
#pragma unroll
  for (int nf = 0; nf < 3; ++nf){
    const ushort_t* p = Wp + (size_t)(cb*64 + nf*16 + lane16)*KTOT + w*320 + q4*8;
#pragma unroll
    for (int kf = 0; kf < 10; ++kf)
      wfr[nf][kf] = *(const s16x8*)(p + kf*32);
  }
  // ---- weights nf=3 (16 cols, full K) into LDS ----
  {
    int c = tid >> 5, kc = tid & 31;
    const ushort_t* src = Wp + (size_t)(cb*64 + 48 + c)*KTOT;
    for (int k8 = kc*8; k8 < KTOT; k8 += 256)
      *(s16x8*)((char*)&wlds[c][0] + (size_t)k8*2) = *(const s16x8*)(src + k8);
  }
  // ---- bias: only wave 0 seeds acc with it (summed through reduction) ----
  float binit[4];
#pragma unroll
  for (int nf = 0; nf < 4; ++nf)
    binit[nf] = (w==0) ? bias[cb*64 + nf*16 + lane16] : 0.f;

  // ---- per-lane A byte-offsets for 4 m-frags ----
  int vo0 = ((rt*64 +  0 + lane16)*KTOT + w*320 + q4*8)*2;
  int vo1 = ((rt*64 + 16 + lane16)*KTOT + w*320 + q4*8)*2;
  int vo2 = ((rt*64 + 32 + lane16)*KTOT + w*320 + q4*8)*2;
  int vo3 = ((rt*64 + 48 + lane16)*KTOT + w*320 + q4*8)*2;
  const char* wbase = (const char*)wlds + (size_t)lane16*5136 + (w*320 + q4*8)*2;

  // x/h region per (w,kf): k = w*320 + kf*32; h-part iff k >= 512
  const int kwb = w*320;
  const bool sc_0 = kwb       >= KIN, sc_1 = kwb+ 32 >= KIN, sc_2 = kwb+ 64 >= KIN,
             sc_3 = kwb+ 96  >= KIN, sc_4 = kwb+128 >= KIN, sc_5 = kwb+160 >= KIN,
             sc_6 = kwb+192  >= KIN, sc_7 = kwb+224 >= KIN, sc_8 = kwb+256 >= KIN,
             sc_9 = kwb+288  >= KIN;

  // ---- epilogue constants: 2 h-elems per thread ----
  const int e0   = tid*2;
  const int erow = e0 >> 4;          // 0..63
  const int ehc  = e0 & 15;          // even
  const int s8l  = ehc >> 3, jj = ehc & 7;
  const int crow = rt*64 + erow;
  const int hcol = cb*16 + ehc;
  float c0 = 0.f, c1 = 0.f;

  unsigned* grp  = bar + (bid & 7)*32;
  unsigned* root = bar + 512;
  unsigned* rel  = bar + 544;

  __syncthreads();                   // wlds ready

#pragma unroll 1
  for (int t = 0; t < T_STEPS; ++t){
    const char* pA = (const char*)xh_c + (size_t)t*BATCH*KTOT*2;
    const char* aB0 = pA + vo0;
    const char* aB1 = pA + vo1;
    const char* aB2 = pA + vo2;
    const char* aB3 = pA + vo3;
    f32x4 acc[4][4];
#pragma unroll
    for (int mf = 0; mf < 4; ++mf)
#pragma unroll
      for (int nf = 0; nf < 4; ++nf)
        acc[mf][nf] = (f32x4){binit[nf], binit[nf], binit[nf], binit[nf]};

    s16x8 p0,p1,p2,p3, q0,q1,q2,q3;
    ISSUE(p, "0",   sc_0); ISSUE(q, "64",  sc_1);
    WAITV(4); SCHED0(); COMP(p, 0); ISSUE(p, "128", sc_2);
    WAITV(4); SCHED0(); COMP(q, 1); ISSUE(q, "192", sc_3);
    WAITV(4); SCHED0(); COMP(p, 2); ISSUE(p, "256", sc_4);
    WAITV(4); SCHED0(); COMP(q, 3); ISSUE(q, "320", sc_5);
    WAITV(4); SCHED0(); COMP(p, 4); ISSUE(p, "384", sc_6);
    WAITV(4); SCHED0(); COMP(q, 5); ISSUE(q, "448", sc_7);
    WAITV(4); SCHED0(); COMP(p, 6); ISSUE(p, "512", sc_8);
    WAITV(4); SCHED0(); COMP(q, 7); ISSUE(q, "576", sc_9);
    WAITV(4); SCHED0(); COMP(p, 8);
    WAITV(0); SCHED0(); COMP(q, 9);

    // ---- reduction: s0 = w0+w2+w4+w6, s1 = w1+w3+w5+w7 (b128 ops) ----
#define REDW(FIRST) do{ \
    float* rbase = &red[w&1][0][0]; \
    _Pragma("unroll") \
    for (int mf = 0; mf < 4; ++mf){ \
      _Pragma("unroll") \
      for (int nf = 0; nf < 4; ++nf){ \
        float* p_ = rbase + (nf*16+lane16)*68 + mf*16 + q4*4; \
        if (FIRST) *(f32x4*)p_ = acc[mf][nf]; \
        else { f32x4 v_ = *(const f32x4*)p_; v_ += acc[mf][nf]; *(f32x4*)p_ = v_; } \
      } } }while(0)

    if (w==4 || w==5) REDW(true);
    __syncthreads();
    if (w==6 || w==7) REDW(false);
    __syncthreads();
    if (w==2 || w==3) REDW(false);
    __syncthreads();
    if (w==0 || w==1) REDW(false);
    __syncthreads();

    // ---- epilogue: gates, c (regs), h (sc1 store) ----
    {
      const float* r0 = &red[0][0][0];
      const float* r1 = &red[1][0][0];
      int cbase = (s8l*32 + jj)*68 + erow;
      float gi0 = r0[cbase      ] + r1[cbase      ];
      float gi1 = r0[cbase+68   ] + r1[cbase+68   ];
      float gf0 = r0[cbase+544  ] + r1[cbase+544  ];
      float gf1 = r0[cbase+612  ] + r1[cbase+612  ];
      float go0 = r0[cbase+1088 ] + r1[cbase+1088 ];
      float go1 = r0[cbase+1156 ] + r1[cbase+1156 ];
      float gc0 = r0[cbase+1632 ] + r1[cbase+1632 ];
      float gc1 = r0[cbase+1700 ] + r1[cbase+1700 ];
      c0 = sigmoidf_(gf0)*c0 + sigmoidf_(gi0)*tanhf_(gc0);
      c1 = sigmoidf_(gf1)*c1 + sigmoidf_(gi1)*tanhf_(gc1);
      float hn0 = sigmoidf_(go0)*tanhf_(c0);
      float hn1 = sigmoidf_(go1)*tanhf_(c1);
      unsigned hpack = ((unsigned)f2bf(hn1) << 16) | (unsigned)f2bf(hn0);
      ushort_t* hptr = xh + ((size_t)(t+1)*BATCH + crow)*KTOT + KIN + hcol;
      store_u32_sc(hptr, hpack);
      if (t == T_STEPS-1){
        cbuf[(size_t)crow*HDIM + hcol  ] = c0;
        cbuf[(size_t)crow*HDIM + hcol+1] = c1;
      }
    }

    // ---- relaxed-atomic grid barrier (monotonic counters, no fences) ----
    if (t < T_STEPS-1){
      __syncthreads();               // drains vmcnt: all sc1 h-stores retired
      if (tid == 0){
        unsigned old = __hip_atomic_fetch_add(grp, 1u,
                          __ATOMIC_RELAXED, __HIP_MEMORY_SCOPE_AGENT);
        if (old == (unsigned)(t*32 + 31)){
          unsigned r2 = __hip_atomic_fetch_add(root, 1u,
                          __ATOMIC_RELAXED, __HIP_MEMORY_SCOPE_AGENT);
          if (r2 == (unsigned)(t*8 + 7))
            __hip_atomic_store(rel, (unsigned)(t+1),
                          __ATOMIC_RELAXED, __HIP_MEMORY_SCOPE_AGENT);
        }
        while (__hip_atomic_load(rel, __ATOMIC_RELAXED,
                                 __HIP_MEMORY_SCOPE_AGENT) < (unsigned)(t+1))
          __builtin_amdgcn_s_sleep(1);
      }
      __syncthreads();
    }
  }
#undef REDW
}

// ---------------- output GEMM: [16384,2048]x[2048,512] + fc_b ----------------
__global__ __launch_bounds__(256) void out_gemm(const ushort_t* __restrict__ A,
                                                const ushort_t* __restrict__ Bt,
                                                const float* __restrict__ fcb,
                                                float* __restrict__ out){
  __shared__ alignas(16) ushort_t Alds[3][4096];
  __shared__ alignas(16) ushort_t Blds[3][4096];
  const int tid = threadIdx.x;
  const int l = tid & 63, w = tid >> 6;
  const int b = blockIdx.x;
  const int orig = (b & 7)*256 + (b >> 3);
  const int rowt = orig >> 3;
  const int colt = orig & 7;
  const int sc = (l&7) ^ (l>>3);
  const int q4 = l>>4, d = l&7;
  const int swz0 = (q4 ^ d) << 4;
  const int swz1 = ((4+q4) ^ d) << 4;
  const int mrow0 = ((w>>1)*32) + (l&15);
  const int nrow0 = ((w&1)*32) + (l&15);
  f32x4 acc[2][2] = {};

  auto stage = [&](int kt, int buf){
    int k0 = kt*64;
#pragma unroll
    for (int q = 0; q < 2; ++q){
      int rowl = q*32 + w*8 + (l>>3);
      gload16(A  + (size_t)(rowt*64 + rowl)*KTOT + k0 + sc*8, &Alds[buf][(q*32+w*8)*64]);
      gload16(Bt + (size_t)(colt*64 + rowl)*HDIM + k0 + sc*8, &Blds[buf][(q*32+w*8)*64]);
    }
  };

  stage(0, 0); stage(1, 1); stage(2, 2);
  int buf = 0;
  for (int kt = 0; kt < 32; ++kt){
    if (kt < 30)       { WAITV(8); }
    else if (kt == 30) { WAITV(4); }
    else               { WAITV(0); }
    SBAR();
    const char* pa = (const char*)Alds[buf];
    const char* pb = (const char*)Blds[buf];
#pragma unroll
    for (int s = 0; s < 2; ++s){
      int swz = s ? swz1 : swz0;
      s16x8 a0 = *(const s16x8*)(pa + mrow0*128 + swz);
      s16x8 a1 = *(const s16x8*)(pa + (mrow0+16)*128 + swz);
      s16x8 b0 = *(const s16x8*)(pb + nrow0*128 + swz);
      s16x8 b1 = *(const s16x8*)(pb + (nrow0+16)*128 + swz);
      acc[0][0] = mfma16(a0, b0, acc[0][0]);
      acc[0][1] = mfma16(a0, b1, acc[0][1]);
      acc[1][0] = mfma16(a1, b0, acc[1][0]);
      acc[1][1] = mfma16(a1, b1, acc[1][1]);
    }
    SBAR();
    if (kt+3 < 32) stage(kt+3, buf);
    buf = (buf==2) ? 0 : buf+1;
  }
#pragma unroll
  for (int m = 0; m < 2; ++m){
#pragma unroll
    for (int f = 0; f < 2; ++f){
      int col = colt*64 + (w&1)*32 + f*16 + (l&15);
      float bb = fcb[col];
#pragma unroll
      for (int r = 0; r < 4; ++r){
        int row = rowt*64 + (w>>1)*32 + m*16 + q4*4 + r;
        out[(size_t)row*OUTDIM + col] = acc[m][f][r] + bb;
      }
    }
  }
}

// final h (bf16->f32) into d_out; c written by lstm_seq directly
__global__ __launch_bounds__(256) void finalize(const ushort_t* __restrict__ xh,
                                                float* __restrict__ out){
  int i = blockIdx.x*256 + threadIdx.x;            // 131072 threads
  for (; i < BATCH*HDIM; i += 131072){
    int r = i >> 11, k = i & 2047;
    out[(size_t)T_STEPS*BATCH*OUTDIM + i] =
        bf2f(xh[((size_t)T_STEPS*BATCH + r)*KTOT + KIN + k]);
  }
}

extern "C" void kernel_launch(void* const* d_in, const int* in_sizes, int n_in,
                              void* d_out, int out_size, void* d_ws, size_t ws_size,
                              hipStream_t stream){
  const float* x   = (const float*)d_in[0];
  const float* Wx  = (const float*)d_in[1];
  const float* Wh  = (const float*)d_in[2];
  const float* bx  = (const float*)d_in[3];
  const float* bh  = (const float*)d_in[4];
  const float* fcw = (const float*)d_in[5];
  const float* fcb = (const float*)d_in[6];
  float* out = (float*)d_out;
  char* ws = (char*)d_ws;

  // ws layout (bytes)
  ushort_t* Wp   = (ushort_t*)(ws + 0);              // 41,943,040
  ushort_t* fcwT = (ushort_t*)(ws + 41943040);       //  2,097,152
  ushort_t* xh   = (ushort_t*)(ws + 44040192);       // 84,541,440 (129 x 128 x 2560 bf16)
  float*    bias = (float*)   (ws + 128581632);      //     32,768
  unsigned* bar  = (unsigned*)(ws + 128614400);      //      4,096
  if (ws_size < (size_t)128618496) return;           // insufficient scratch

  // c state written directly into its output slot: out + T*B*O + B*H
  float* cbuf = out + (size_t)T_STEPS*BATCH*OUTDIM + (size_t)BATCH*HDIM;

  pack_w  <<<NKT*128, 256, 0, stream>>>(Wx, Wh, Wp);
  pack_fcw<<<32*8,    256, 0, stream>>>(fcw, fcwT);
  prep    <<<4096,    256, 0, stream>>>(x, bx, bh, xh, bias, bar);
  lstm_seq<<<256, 512, 0, stream>>>(xh, xh, Wp, bias, cbuf, bar);
  out_gemm<<<2048, 256, 0, stream>>>(xh + (size_t)BATCH*KTOT + KIN, fcwT, fcb, out);
  finalize<<<512, 256, 0, stream>>>(xh, out);
}